// Round 2
// 919.535 us; speedup vs baseline: 1.0407x; 1.0407x over previous
//
#include <hip/hip_runtime.h>
#include <cstdint>
#include <cstddef>

#define VOCAB 32000
#define EMB 512
#define HID 1024
#define SEQ 512
#define BATCH 128
#define SPLIT 8     // s-dimension splits per batch element in attention pass
#define NCHUNK 7    // k-splits in gates GEMM (5 x 512 of W_ih, 2 x 512 of W_hh)

typedef __bf16 bf16x8 __attribute__((ext_vector_type(8)));
typedef short  s16x8  __attribute__((ext_vector_type(8)));
typedef float  f32x4  __attribute__((ext_vector_type(4)));
typedef float  fvec4  __attribute__((ext_vector_type(4)));

__device__ __forceinline__ float sigmoidf_(float x) { return 1.f / (1.f + __expf(-x)); }

// fp32 -> bf16 (RNE), bit-level to avoid relying on __bf16 cast lowering
__device__ __forceinline__ unsigned short f2bu(float f) {
    union { float f; uint32_t u; } v; v.f = f;
    return (unsigned short)((v.u + 0x7FFFu + ((v.u >> 16) & 1u)) >> 16);
}

__device__ __forceinline__ bf16x8 cvt_bf8(float4 a, float4 b) {
    union { s16x8 s; bf16x8 b; } u;
    u.s[0] = (short)f2bu(a.x); u.s[1] = (short)f2bu(a.y);
    u.s[2] = (short)f2bu(a.z); u.s[3] = (short)f2bu(a.w);
    u.s[4] = (short)f2bu(b.x); u.s[5] = (short)f2bu(b.y);
    u.s[6] = (short)f2bu(b.z); u.s[7] = (short)f2bu(b.w);
    return u.b;
}

__device__ __forceinline__ bf16x8 load_bf8(const unsigned short* p) {
    union { s16x8 s; bf16x8 b; } u;
    u.s = *(const s16x8*)p;
    return u.b;
}

// nontemporal float4 load via native ext-vector type (builtin rejects
// HIP_vector_type); streamed-once data: enc, W_ih/W_hh, W_fc
__device__ __forceinline__ float4 ldnt4(const float* p) {
    fvec4 v = __builtin_nontemporal_load((const fvec4*)p);
    return make_float4(v.x, v.y, v.z, v.w);
}

// ---------------------------------------------------------------------------
// Fused attention: single pass over encoder_states (512 MB), ~HBM roofline.
// relu(energy) >= 0 and small => exp without max-subtraction is safe.
// chnk==0 blocks additionally emit hid_bf = bf16(hidden[b]) (free: hv is
// already in registers) -- this replaces the old init_k.
// ---------------------------------------------------------------------------
__global__ __launch_bounds__(256, 4) void attn_k(
    const float* __restrict__ enc, const float* __restrict__ hidden,
    const float* __restrict__ W_e, const float* __restrict__ b_e,
    float* __restrict__ ctxPartial, float* __restrict__ lPartial,
    unsigned short* __restrict__ hid_bf)
{
    const int blk  = blockIdx.x;
    const int b    = blk >> 3;
    const int chnk = blk & 7;
    const int t    = threadIdx.x;
    const int wave = t >> 6;
    const int lane = t & 63;

    __shared__ float red[4];
    __shared__ float l_sh[4];
    __shared__ float ctx_sh[4][2048];

    float4 hv = *(const float4*)&hidden[(size_t)b * HID + t * 4];
    if (chnk == 0) {
        // hidden -> bf16 A-operand for the W_hh part of the gates GEMM
        unsigned short hb[4] = { f2bu(hv.x), f2bu(hv.y), f2bu(hv.z), f2bu(hv.w) };
        *(uint2*)&hid_bf[(size_t)b * HID + t * 4] = *(const uint2*)hb;
    }
    float4 wv = *(const float4*)&W_e[t * 4];
    float hl = hv.x * wv.x + hv.y * wv.y + hv.z * wv.z + hv.w * wv.w;
    #pragma unroll
    for (int off = 32; off > 0; off >>= 1) hl += __shfl_down(hl, off, 64);
    if (lane == 0) red[wave] = hl;
    __syncthreads();
    const float hdot = red[0] + red[1] + red[2] + red[3] + b_e[0];

    float4 w[8];
    #pragma unroll
    for (int j = 0; j < 8; j++)
        w[j] = *(const float4*)&W_e[HID + j * 256 + lane * 4];

    float4 c[8];
    #pragma unroll
    for (int j = 0; j < 8; j++) c[j] = make_float4(0.f, 0.f, 0.f, 0.f);
    float lsum = 0.f;

    #pragma unroll 1
    for (int i = 0; i < 16; i++) {
        const int s = chnk * 64 + wave + i * 4;
        const float* p = enc + ((size_t)s * BATCH + b) * 2048;
        float4 e[8];
        #pragma unroll
        for (int j = 0; j < 8; j++)
            e[j] = ldnt4(&p[j * 256 + lane * 4]);
        float d = 0.f;
        #pragma unroll
        for (int j = 0; j < 8; j++)
            d += e[j].x * w[j].x + e[j].y * w[j].y + e[j].z * w[j].z + e[j].w * w[j].w;
        #pragma unroll
        for (int off = 32; off > 0; off >>= 1) d += __shfl_xor(d, off, 64);
        float energy = d + hdot;
        energy = energy > 0.f ? energy : 0.f;
        const float pr = __expf(energy);
        lsum += pr;
        #pragma unroll
        for (int j = 0; j < 8; j++) {
            c[j].x += pr * e[j].x; c[j].y += pr * e[j].y;
            c[j].z += pr * e[j].z; c[j].w += pr * e[j].w;
        }
    }

    #pragma unroll
    for (int j = 0; j < 8; j++)
        *(float4*)&ctx_sh[wave][j * 256 + lane * 4] = c[j];
    if (lane == 0) l_sh[wave] = lsum;
    __syncthreads();

    float* outp = ctxPartial + (size_t)blk * 2048;
    #pragma unroll
    for (int j = 0; j < 8; j++) {
        const int idx = j * 256 + t;
        outp[idx] = ctx_sh[0][idx] + ctx_sh[1][idx] + ctx_sh[2][idx] + ctx_sh[3][idx];
    }
    if (t == 0) lPartial[blk] = l_sh[0] + l_sh[1] + l_sh[2] + l_sh[3];
}

// ---------------------------------------------------------------------------
// Combine partials -> normalized context (bf16) + embedding gather (bf16).
// rnn_bf[b, 0:2048] = context, rnn_bf[b, 2048:2560] = emb_table[x[b]]
// ---------------------------------------------------------------------------
__global__ void combine_k(const float* __restrict__ ctxPartial,
                          const float* __restrict__ lPartial,
                          const int* __restrict__ x,
                          const float* __restrict__ emb_table,
                          unsigned short* __restrict__ rnn_bf)
{
    const int b = blockIdx.x;
    const int t = threadIdx.x;
    float L = 0.f;
    #pragma unroll
    for (int cN = 0; cN < SPLIT; cN++) L += lPartial[b * SPLIT + cN];
    const float inv = 1.f / L;
    unsigned short* out = rnn_bf + (size_t)b * 2560;
    #pragma unroll
    for (int j = 0; j < 8; j++) {
        const int h = j * 256 + t;
        float v = 0.f;
        #pragma unroll
        for (int cN = 0; cN < SPLIT; cN++)
            v += ctxPartial[((size_t)(b * SPLIT + cN)) * 2048 + h];
        out[h] = f2bu(v * inv);
    }
    const int tok = x[b];
    for (int e2 = t; e2 < EMB; e2 += 256)
        out[2048 + e2] = f2bu(emb_table[(size_t)tok * EMB + e2]);
}

// ---------------------------------------------------------------------------
// gP[chunk] = X_bf @ W^T slice via MFMA, fp32 W converted to bf16 in-regs.
// Grid: (64 n-blocks, 7 k-chunks). Chunks 0..4: rnn_bf/W_ih (k=2560 in 512s);
// chunks 5..6: hid_bf/W_hh (k=1024 in 512s).
// Plain stores to per-chunk partial slabs (no atomics, no init needed --
// every chunk writes its complete [128 x 4096] slab).
// ---------------------------------------------------------------------------
__global__ __launch_bounds__(256) void gates_mfma_k(
    float* __restrict__ gP,
    const unsigned short* __restrict__ rnn_bf, const unsigned short* __restrict__ hid_bf,
    const float* __restrict__ W_ih, const float* __restrict__ W_hh)
{
    const int chunk = blockIdx.y;
    const unsigned short* X; const float* W; int Kx, Kw;
    if (chunk < 5) { X = rnn_bf + chunk * 512; W = W_ih + chunk * 512; Kx = 2560; Kw = 2560; }
    else           { X = hid_bf + (chunk - 5) * 512; W = W_hh + (chunk - 5) * 512; Kx = 1024; Kw = 1024; }

    const int t    = threadIdx.x;
    const int wave = t >> 6;
    const int lane = t & 63;
    const int ln   = lane & 15;
    const int q    = lane >> 4;
    const int n0   = (blockIdx.x * 4 + wave) * 16;

    f32x4 acc[8];
    #pragma unroll
    for (int mt = 0; mt < 8; mt++) acc[mt] = (f32x4){0.f, 0.f, 0.f, 0.f};

    const float* wrow = W + (size_t)(n0 + ln) * Kw;

    #pragma unroll 2
    for (int kk = 0; kk < 512; kk += 32) {
        const int k = kk + q * 8;
        float4 b0 = ldnt4(&wrow[k]);
        float4 b1 = ldnt4(&wrow[k + 4]);
        bf16x8 bf = cvt_bf8(b0, b1);
        #pragma unroll
        for (int mt = 0; mt < 8; mt++) {
            bf16x8 af = load_bf8(&X[(size_t)(mt * 16 + ln) * Kx + k]);
            acc[mt] = __builtin_amdgcn_mfma_f32_16x16x32_bf16(af, bf, acc[mt], 0, 0, 0);
        }
    }

    float* outp = gP + (size_t)chunk * (BATCH * 4 * HID);
    #pragma unroll
    for (int mt = 0; mt < 8; mt++) {
        #pragma unroll
        for (int r = 0; r < 4; r++) {
            const int m = mt * 16 + q * 4 + r;
            outp[(size_t)m * (4 * HID) + n0 + ln] = acc[mt][r];
        }
    }
}

// ---------------------------------------------------------------------------
// LSTM pointwise: sum the 7 k-split partials + biases, apply gate math.
// Also emits h_bf (bf16) as A-operand for the FC GEMM.
// ---------------------------------------------------------------------------
__global__ void lstm_k(const float* __restrict__ gP,
                       const float* __restrict__ b_ih, const float* __restrict__ b_hh,
                       const float* __restrict__ cell,
                       float* __restrict__ h_out, float* __restrict__ c_out,
                       unsigned short* __restrict__ h_bf)
{
    const int idx = blockIdx.x * 256 + threadIdx.x;
    const int b = idx >> 10;
    const int h = idx & 1023;
    float g0 = b_ih[h]            + b_hh[h];
    float g1 = b_ih[HID + h]      + b_hh[HID + h];
    float g2 = b_ih[2 * HID + h]  + b_hh[2 * HID + h];
    float g3 = b_ih[3 * HID + h]  + b_hh[3 * HID + h];
    const float* base = gP + (size_t)b * (4 * HID);
    #pragma unroll
    for (int cN = 0; cN < NCHUNK; cN++) {
        const float* p = base + (size_t)cN * (BATCH * 4 * HID);
        g0 += p[h];
        g1 += p[HID + h];
        g2 += p[2 * HID + h];
        g3 += p[3 * HID + h];
    }
    const float ig = sigmoidf_(g0);
    const float fg = sigmoidf_(g1);
    const float gg = tanhf(g2);
    const float og = sigmoidf_(g3);
    const float cn = fg * cell[idx] + ig * gg;
    const float hn = og * tanhf(cn);
    c_out[idx] = cn;
    h_out[idx] = hn;
    h_bf[idx] = f2bu(hn);
}

// ---------------------------------------------------------------------------
// pred = h_bf @ W_fc^T + b_fc via MFMA (fp32 W -> bf16 in-registers).
// 500 blocks x 4 waves, wave = one 16-col n-tile, full K=1024, no atomics.
// ---------------------------------------------------------------------------
__global__ __launch_bounds__(256) void fc_mfma_k(
    float* __restrict__ pred, const unsigned short* __restrict__ h_bf,
    const float* __restrict__ W_fc, const float* __restrict__ b_fc)
{
    const int t    = threadIdx.x;
    const int wave = t >> 6;
    const int lane = t & 63;
    const int ln   = lane & 15;
    const int q    = lane >> 4;
    const int n0   = (blockIdx.x * 4 + wave) * 16;

    f32x4 acc[8];
    #pragma unroll
    for (int mt = 0; mt < 8; mt++) acc[mt] = (f32x4){0.f, 0.f, 0.f, 0.f};

    const float* wrow = W_fc + (size_t)(n0 + ln) * HID;

    #pragma unroll 2
    for (int kk = 0; kk < HID; kk += 32) {
        const int k = kk + q * 8;
        float4 b0 = ldnt4(&wrow[k]);
        float4 b1 = ldnt4(&wrow[k + 4]);
        bf16x8 bf = cvt_bf8(b0, b1);
        #pragma unroll
        for (int mt = 0; mt < 8; mt++) {
            bf16x8 af = load_bf8(&h_bf[(size_t)(mt * 16 + ln) * HID + k]);
            acc[mt] = __builtin_amdgcn_mfma_f32_16x16x32_bf16(af, bf, acc[mt], 0, 0, 0);
        }
    }

    const float bias = b_fc[n0 + ln];
    #pragma unroll
    for (int mt = 0; mt < 8; mt++) {
        #pragma unroll
        for (int r = 0; r < 4; r++) {
            const int m = mt * 16 + q * 4 + r;
            pred[(size_t)m * VOCAB + n0 + ln] = acc[mt][r] + bias;
        }
    }
}

// ---------------------------------------------------------------------------
extern "C" void kernel_launch(void* const* d_in, const int* in_sizes, int n_in,
                              void* d_out, int out_size, void* d_ws, size_t ws_size,
                              hipStream_t stream)
{
    const int*   x      = (const int*)  d_in[0];
    const float* enc    = (const float*)d_in[1];
    const float* hidden = (const float*)d_in[2];
    const float* cell   = (const float*)d_in[3];
    const float* emb    = (const float*)d_in[4];
    const float* W_e    = (const float*)d_in[5];
    const float* b_e    = (const float*)d_in[6];
    const float* W_ih   = (const float*)d_in[7];
    const float* W_hh   = (const float*)d_in[8];
    const float* b_ih   = (const float*)d_in[9];
    const float* b_hh   = (const float*)d_in[10];
    const float* W_fc   = (const float*)d_in[11];
    const float* b_fc   = (const float*)d_in[12];

    float* pred  = (float*)d_out;                       // [128, 32000]
    float* h_out = pred + (size_t)BATCH * VOCAB;        // [128, 1024]
    float* c_out = h_out + BATCH * HID;                 // [128, 1024]

    float* ws         = (float*)d_ws;
    float* ctxPartial = ws;                                        // 2,097,152 f
    float* lPartial   = ctxPartial + (size_t)BATCH * SPLIT * 2048; // 1,024 f
    float* gP         = lPartial + BATCH * SPLIT;                  // 7 * 524,288 f
    unsigned short* rnn_bf = (unsigned short*)(gP + (size_t)NCHUNK * BATCH * 4 * HID); // 128*2560
    unsigned short* hid_bf = rnn_bf + (size_t)BATCH * 2560;        // 128*1024
    unsigned short* h_bf   = hid_bf + (size_t)BATCH * HID;         // 128*1024

    // 1) fused attention (single NT pass over 512 MB encoder_states);
    //    chnk==0 blocks also emit hid_bf (replaces old init_k)
    attn_k<<<BATCH * SPLIT, 256, 0, stream>>>(enc, hidden, W_e, b_e,
                                              ctxPartial, lPartial, hid_bf);
    // 2) normalize + embedding gather -> rnn_bf (bf16)
    combine_k<<<BATCH, 256, 0, stream>>>(ctxPartial, lPartial, x, emb, rnn_bf);
    // 3) gP[c] = [rnn,hid] @ [W_ih,W_hh]^T slices (MFMA, 7-way k-split, no atomics)
    gates_mfma_k<<<dim3(64, NCHUNK), 256, 0, stream>>>(gP, rnn_bf, hid_bf, W_ih, W_hh);
    // 4) LSTM pointwise (sums 7 partials + biases) -> h_new, c_new, h_bf
    lstm_k<<<(BATCH * HID) / 256, 256, 0, stream>>>(gP, b_ih, b_hh, cell,
                                                    h_out, c_out, h_bf);
    // 5) pred = h_bf @ W_fc^T + b_fc  (MFMA, 500 blocks, no atomics)
    fc_mfma_k<<<VOCAB / 64, 256, 0, stream>>>(pred, h_bf, W_fc, b_fc);
}